// Round 1
// baseline (4480.900 us; speedup 1.0000x reference)
//
#include <hip/hip_runtime.h>
#include <hip/hip_bf16.h>

// SGConv (K=2) on MI355X.
// Key algebraic transform: propagation is linear, so
//   log_softmax(A^2 x W^T + b) == log_softmax(A^2 (x W^T) + b)
// Project N x 512 -> N x 40 FIRST, then propagate 40-wide (12.8x less traffic).

#define TPB 256

// ---- degree ------------------------------------------------------------
__global__ void k_init_deg(float* __restrict__ deg, int N) {
    int i = blockIdx.x * TPB + threadIdx.x;
    if (i < N) deg[i] = 1.0f;               // self-loop contributes 1
}

__global__ void k_accum_deg(const int* __restrict__ dst, float* __restrict__ deg, int E) {
    int e = blockIdx.x * TPB + threadIdx.x;
    if (e < E) atomicAdd(&deg[dst[e]], 1.0f);
}

__global__ void k_rsqrt(float* __restrict__ deg, int N) {
    int i = blockIdx.x * TPB + threadIdx.x;
    if (i < N) deg[i] = rsqrtf(deg[i]);     // deg >= 1 always (self-loop)
}

// ---- y0 = x @ W^T  (N x 512) * (40 x 512)^T -> N x 40 ------------------
__global__ __launch_bounds__(TPB) void k_matmul_xwt(
    const float* __restrict__ x, const float* __restrict__ W,
    float* __restrict__ y, int N) {
    int row = blockIdx.x * TPB + threadIdx.x;
    if (row >= N) return;
    float acc[40];
#pragma unroll
    for (int c = 0; c < 40; ++c) acc[c] = 0.f;
    const float4* xr = reinterpret_cast<const float4*>(x + (size_t)row * 512);
    for (int k4 = 0; k4 < 128; ++k4) {
        float4 xv = xr[k4];
#pragma unroll
        for (int c = 0; c < 40; ++c) {
            // W index is wave-uniform -> scalar/L2 path
            float4 wv = *reinterpret_cast<const float4*>(&W[c * 512 + k4 * 4]);
            acc[c] = fmaf(xv.x, wv.x,
                     fmaf(xv.y, wv.y,
                     fmaf(xv.z, wv.z,
                     fmaf(xv.w, wv.w, acc[c]))));
        }
    }
    float4* yo = reinterpret_cast<float4*>(y + (size_t)row * 40);
#pragma unroll
    for (int c4 = 0; c4 < 10; ++c4)
        yo[c4] = make_float4(acc[c4*4], acc[c4*4+1], acc[c4*4+2], acc[c4*4+3]);
}

// ---- one propagation hop: yout[dst] += dinv[src]*dinv[dst] * yin[src] --
// task = (edge_or_selfloop, chunk of 4 floats), 10 chunks per edge.
__global__ __launch_bounds__(TPB) void k_hop(
    const int* __restrict__ src, const int* __restrict__ dst,
    const float* __restrict__ dinv,
    const float* __restrict__ yin, float* __restrict__ yout,
    int E, int N) {
    int idx = blockIdx.x * TPB + threadIdx.x;          // < (E+N)*10 < 2^31
    int total = (E + N) * 10;
    if (idx >= total) return;
    int e  = idx / 10;                                  // magic-mul div
    int c4 = idx - e * 10;
    int s, d;
    if (e < E) { s = src[e]; d = dst[e]; }
    else       { s = e - E;  d = s;      }              // self-loop
    float w = dinv[s] * dinv[d];
    float4 v = *reinterpret_cast<const float4*>(&yin[(size_t)s * 40 + c4 * 4]);
    float* o = &yout[(size_t)d * 40 + c4 * 4];
    atomicAdd(o + 0, w * v.x);
    atomicAdd(o + 1, w * v.y);
    atomicAdd(o + 2, w * v.z);
    atomicAdd(o + 3, w * v.w);
}

// ---- log_softmax rows, in place on d_out, + bias -----------------------
__global__ __launch_bounds__(TPB) void k_logsoftmax(
    float* __restrict__ out, const float* __restrict__ b, int N) {
    int r = blockIdx.x * TPB + threadIdx.x;
    if (r >= N) return;
    float4* rowp = reinterpret_cast<float4*>(out + (size_t)r * 40);
    float v[40];
    float m = -1e30f;
#pragma unroll
    for (int c4 = 0; c4 < 10; ++c4) {
        float4 t = rowp[c4];
        v[c4*4+0] = t.x + b[c4*4+0];
        v[c4*4+1] = t.y + b[c4*4+1];
        v[c4*4+2] = t.z + b[c4*4+2];
        v[c4*4+3] = t.w + b[c4*4+3];
    }
#pragma unroll
    for (int c = 0; c < 40; ++c) m = fmaxf(m, v[c]);
    float sum = 0.f;
#pragma unroll
    for (int c = 0; c < 40; ++c) sum += __expf(v[c] - m);
    float lse = m + __logf(sum);
#pragma unroll
    for (int c4 = 0; c4 < 10; ++c4)
        rowp[c4] = make_float4(v[c4*4+0]-lse, v[c4*4+1]-lse, v[c4*4+2]-lse, v[c4*4+3]-lse);
}

extern "C" void kernel_launch(void* const* d_in, const int* in_sizes, int n_in,
                              void* d_out, int out_size, void* d_ws, size_t ws_size,
                              hipStream_t stream) {
    const float* x  = (const float*)d_in[0];
    const int*   ei = (const int*)d_in[1];
    const float* W  = (const float*)d_in[2];
    const float* b  = (const float*)d_in[3];
    float* out = (float*)d_out;

    const int N = in_sizes[0] / 512;     // 100000
    const int E = in_sizes[1] / 2;       // 3200000
    const int* src = ei;                 // edge_index[0]
    const int* dst = ei + E;             // edge_index[1]

    // workspace layout (floats): y0 [N*40] | y1 [N*40] | deg/dinv [N]
    float* y0  = (float*)d_ws;
    float* y1  = y0 + (size_t)N * 40;
    float* deg = y1 + (size_t)N * 40;

    // zero accumulation targets (y1 and d_out); y0 is written directly
    hipMemsetAsync(y1,  0, (size_t)N * 40 * sizeof(float), stream);
    hipMemsetAsync(out, 0, (size_t)N * 40 * sizeof(float), stream);

    int gN = (N + TPB - 1) / TPB;
    int gE = (E + TPB - 1) / TPB;
    int total = (E + N) * 10;
    int gH = (total + TPB - 1) / TPB;

    k_init_deg<<<gN, TPB, 0, stream>>>(deg, N);
    k_accum_deg<<<gE, TPB, 0, stream>>>(dst, deg, E);
    k_rsqrt<<<gN, TPB, 0, stream>>>(deg, N);

    k_matmul_xwt<<<gN, TPB, 0, stream>>>(x, W, y0, N);

    k_hop<<<gH, TPB, 0, stream>>>(src, dst, deg, y0, y1, E, N);   // hop 1
    k_hop<<<gH, TPB, 0, stream>>>(src, dst, deg, y1, out, E, N);  // hop 2

    k_logsoftmax<<<gN, TPB, 0, stream>>>(out, b, N);
}

// Round 2
// 1085.446 us; speedup vs baseline: 4.1282x; 4.1282x over previous
//
#include <hip/hip_runtime.h>
#include <hip/hip_bf16.h>

// SGConv (K=2) on MI355X.
// R1: replace scatter-atomic propagation (2 GB HBM writeback per hop) with
// on-the-fly dst-CSR + register-accumulated gather (writes 16 MB per hop).
// Normalization folded into data: z = dinv .* h, hop: out[d] = scale * sum z[s].

#define TPB 256
#define SCAN_T 1024

// ---- histogram of incoming-edge counts at dst --------------------------
__global__ void k_hist(const int* __restrict__ dst, int* __restrict__ counts, int E) {
    int e = blockIdx.x * TPB + threadIdx.x;
    if (e < E) atomicAdd(&counts[dst[e]], 1);
}

// ---- single-block exclusive scan + cursor + dinv -----------------------
__global__ __launch_bounds__(SCAN_T) void k_scan(
    const int* __restrict__ counts, int* __restrict__ row_ptr,
    int* __restrict__ cursor, float* __restrict__ dinv, int N) {
    __shared__ int part[SCAN_T];
    int t = threadIdx.x;
    int chunk = (N + SCAN_T - 1) / SCAN_T;
    int beg = t * chunk;
    int end = min(beg + chunk, N);
    int s = 0;
    for (int i = beg; i < end; ++i) s += counts[i];
    part[t] = s;
    __syncthreads();
    for (int off = 1; off < SCAN_T; off <<= 1) {
        int v = (t >= off) ? part[t - off] : 0;
        __syncthreads();
        part[t] += v;
        __syncthreads();
    }
    int run = part[t] - s;          // exclusive prefix for this thread's chunk
    for (int i = beg; i < end; ++i) {
        int c = counts[i];
        row_ptr[i] = run;
        cursor[i]  = run;
        dinv[i]    = rsqrtf((float)(c + 1));   // +1 self-loop
        run += c;
    }
    if (t == SCAN_T - 1) row_ptr[N] = run;     // == E
}

// ---- scatter edges into CSR by dst -------------------------------------
__global__ void k_scatter(const int* __restrict__ src, const int* __restrict__ dst,
                          int* __restrict__ cursor, int* __restrict__ csr, int E) {
    int e = blockIdx.x * TPB + threadIdx.x;
    if (e < E) {
        int pos = atomicAdd(&cursor[dst[e]], 1);
        csr[pos] = src[e];
    }
}

// ---- z0 = dinv .* (x @ W^T)  (N x 512)*(40 x 512)^T -> N x 40 ----------
__global__ __launch_bounds__(TPB) void k_matmul_xwt(
    const float* __restrict__ x, const float* __restrict__ W,
    const float* __restrict__ dinv, float* __restrict__ z, int N) {
    int row = blockIdx.x * TPB + threadIdx.x;
    if (row >= N) return;
    float acc[40];
#pragma unroll
    for (int c = 0; c < 40; ++c) acc[c] = 0.f;
    const float4* xr = reinterpret_cast<const float4*>(x + (size_t)row * 512);
    for (int k4 = 0; k4 < 128; ++k4) {
        float4 xv = xr[k4];
#pragma unroll
        for (int c = 0; c < 40; ++c) {
            float4 wv = *reinterpret_cast<const float4*>(&W[c * 512 + k4 * 4]); // wave-uniform
            acc[c] = fmaf(xv.x, wv.x,
                     fmaf(xv.y, wv.y,
                     fmaf(xv.z, wv.z,
                     fmaf(xv.w, wv.w, acc[c]))));
        }
    }
    float di = dinv[row];
    float4* zo = reinterpret_cast<float4*>(z + (size_t)row * 40);
#pragma unroll
    for (int c4 = 0; c4 < 10; ++c4)
        zo[c4] = make_float4(di*acc[c4*4], di*acc[c4*4+1], di*acc[c4*4+2], di*acc[c4*4+3]);
}

// ---- gather hop: out[d] = dinv[d]^P * (z[d] + sum_{s in N(d)} z[s]) ----
// 10 threads per node, one float4 chunk each; register accumulation.
template <int P>
__global__ __launch_bounds__(TPB) void k_hop_csr(
    const int* __restrict__ csr, const int* __restrict__ row_ptr,
    const float* __restrict__ dinv, const float* __restrict__ zin,
    float* __restrict__ out, int N) {
    int t = blockIdx.x * TPB + threadIdx.x;
    int node = t / 10;
    int c4 = t - node * 10;
    if (node >= N) return;
    const float4* Z = reinterpret_cast<const float4*>(zin);
    float4 acc = Z[node * 10 + c4];            // self-loop term (z includes dinv)
    int beg = row_ptr[node];
    int end = row_ptr[node + 1];
    for (int j = beg; j < end; ++j) {
        int s = csr[j];                        // broadcast across the 10 lanes
        float4 v = Z[s * 10 + c4];
        acc.x += v.x; acc.y += v.y; acc.z += v.z; acc.w += v.w;
    }
    float dd = dinv[node];
    float sc = (P == 2) ? dd * dd : dd;
    float4 o = make_float4(sc*acc.x, sc*acc.y, sc*acc.z, sc*acc.w);
    reinterpret_cast<float4*>(out)[node * 10 + c4] = o;
}

// ---- log_softmax rows, in place on d_out, + bias -----------------------
__global__ __launch_bounds__(TPB) void k_logsoftmax(
    float* __restrict__ out, const float* __restrict__ b, int N) {
    int r = blockIdx.x * TPB + threadIdx.x;
    if (r >= N) return;
    float4* rowp = reinterpret_cast<float4*>(out + (size_t)r * 40);
    float v[40];
    float m = -1e30f;
#pragma unroll
    for (int c4 = 0; c4 < 10; ++c4) {
        float4 t = rowp[c4];
        v[c4*4+0] = t.x + b[c4*4+0];
        v[c4*4+1] = t.y + b[c4*4+1];
        v[c4*4+2] = t.z + b[c4*4+2];
        v[c4*4+3] = t.w + b[c4*4+3];
    }
#pragma unroll
    for (int c = 0; c < 40; ++c) m = fmaxf(m, v[c]);
    float sum = 0.f;
#pragma unroll
    for (int c = 0; c < 40; ++c) sum += __expf(v[c] - m);
    float lse = m + __logf(sum);
#pragma unroll
    for (int c4 = 0; c4 < 10; ++c4)
        rowp[c4] = make_float4(v[c4*4+0]-lse, v[c4*4+1]-lse, v[c4*4+2]-lse, v[c4*4+3]-lse);
}

extern "C" void kernel_launch(void* const* d_in, const int* in_sizes, int n_in,
                              void* d_out, int out_size, void* d_ws, size_t ws_size,
                              hipStream_t stream) {
    const float* x  = (const float*)d_in[0];
    const int*   ei = (const int*)d_in[1];
    const float* W  = (const float*)d_in[2];
    const float* b  = (const float*)d_in[3];
    float* out = (float*)d_out;

    const int N = in_sizes[0] / 512;     // 100000
    const int E = in_sizes[1] / 2;       // 3200000
    const int* src = ei;                 // edge_index[0]
    const int* dst = ei + E;             // edge_index[1]

    // workspace layout: z1 [N*40 f32] | csr [E i32] | counts [N] | row_ptr [N+1] | cursor [N] | dinv [N f32]
    float* z1      = (float*)d_ws;
    int*   csr     = (int*)(z1 + (size_t)N * 40);
    int*   counts  = csr + E;
    int*   row_ptr = counts + N;
    int*   cursor  = row_ptr + N + 1;
    float* dinv    = (float*)(cursor + N);
    float* z0      = out;                // stage z0 in d_out, overwritten by hop2

    hipMemsetAsync(counts, 0, (size_t)N * sizeof(int), stream);

    int gN = (N + TPB - 1) / TPB;
    int gE = (E + TPB - 1) / TPB;
    int gH = (N * 10 + TPB - 1) / TPB;

    k_hist<<<gE, TPB, 0, stream>>>(dst, counts, E);
    k_scan<<<1, SCAN_T, 0, stream>>>(counts, row_ptr, cursor, dinv, N);
    k_scatter<<<gE, TPB, 0, stream>>>(src, dst, cursor, csr, E);

    k_matmul_xwt<<<gN, TPB, 0, stream>>>(x, W, dinv, z0, N);

    k_hop_csr<2><<<gH, TPB, 0, stream>>>(csr, row_ptr, dinv, z0, z1, N);   // hop 1
    k_hop_csr<1><<<gH, TPB, 0, stream>>>(csr, row_ptr, dinv, z1, out, N);  // hop 2

    k_logsoftmax<<<gN, TPB, 0, stream>>>(out, b, N);
}

// Round 3
// 1082.136 us; speedup vs baseline: 4.1408x; 1.0031x over previous
//
#include <hip/hip_runtime.h>
#include <hip/hip_bf16.h>

// SGConv (K=2) on MI355X.
// R1: dst-CSR + gather hops (no atomics on features).
// R2: LDS-tiled coalesced matmul — fixes 2.7x HBM over-fetch (547->205 MB)
//     from thread-per-row strided reads.

#define TPB 256
#define SCAN_T 1024
#define MM_T 128          // matmul block: 128 threads = 128 rows
#define MM_PAD 33         // LDS row stride (floats): bank=(t+k)%32, 2-way free

// ---- histogram of incoming-edge counts at dst --------------------------
__global__ void k_hist(const int* __restrict__ dst, int* __restrict__ counts, int E) {
    int e = blockIdx.x * TPB + threadIdx.x;
    if (e < E) atomicAdd(&counts[dst[e]], 1);
}

// ---- single-block exclusive scan + cursor + dinv -----------------------
__global__ __launch_bounds__(SCAN_T) void k_scan(
    const int* __restrict__ counts, int* __restrict__ row_ptr,
    int* __restrict__ cursor, float* __restrict__ dinv, int N) {
    __shared__ int part[SCAN_T];
    int t = threadIdx.x;
    int chunk = (N + SCAN_T - 1) / SCAN_T;
    int beg = t * chunk;
    int end = min(beg + chunk, N);
    int s = 0;
    for (int i = beg; i < end; ++i) s += counts[i];
    part[t] = s;
    __syncthreads();
    for (int off = 1; off < SCAN_T; off <<= 1) {
        int v = (t >= off) ? part[t - off] : 0;
        __syncthreads();
        part[t] += v;
        __syncthreads();
    }
    int run = part[t] - s;          // exclusive prefix for this thread's chunk
    for (int i = beg; i < end; ++i) {
        int c = counts[i];
        row_ptr[i] = run;
        cursor[i]  = run;
        dinv[i]    = rsqrtf((float)(c + 1));   // +1 self-loop
        run += c;
    }
    if (t == SCAN_T - 1) row_ptr[N] = run;     // == E
}

// ---- scatter edges into CSR by dst -------------------------------------
__global__ void k_scatter(const int* __restrict__ src, const int* __restrict__ dst,
                          int* __restrict__ cursor, int* __restrict__ csr, int E) {
    int e = blockIdx.x * TPB + threadIdx.x;
    if (e < E) {
        int pos = atomicAdd(&cursor[dst[e]], 1);
        csr[pos] = src[e];
    }
}

// ---- z0 = dinv .* (x @ W^T)  — LDS-tiled, coalesced --------------------
__global__ __launch_bounds__(MM_T) void k_matmul_xwt(
    const float* __restrict__ x, const float* __restrict__ W,
    const float* __restrict__ dinv, float* __restrict__ z, int N) {
    __shared__ float xs[MM_T * MM_PAD];
    int t = threadIdx.x;
    int r0 = blockIdx.x * MM_T;
    int row = r0 + t;
    float acc[40];
#pragma unroll
    for (int c = 0; c < 40; ++c) acc[c] = 0.f;

    for (int kc = 0; kc < 16; ++kc) {
        __syncthreads();                        // previous chunk consumed
        // stage 128 rows x 32 floats, coalesced (8 lanes x float4 = 128B/row)
#pragma unroll
        for (int i = 0; i < 8; ++i) {
            int lid = i * MM_T + t;             // 0..1023
            int r  = lid >> 3;
            int c4 = lid & 7;
            if (r0 + r < N) {
                float4 v = *reinterpret_cast<const float4*>(
                    x + (size_t)(r0 + r) * 512 + kc * 32 + c4 * 4);
                int base = r * MM_PAD + c4 * 4;
                xs[base + 0] = v.x; xs[base + 1] = v.y;
                xs[base + 2] = v.z; xs[base + 3] = v.w;
            }
        }
        __syncthreads();
        if (row < N) {
            float xv[32];
#pragma unroll
            for (int k = 0; k < 32; ++k) xv[k] = xs[t * MM_PAD + k];
            const float* Wp = W + kc * 32;
#pragma unroll
            for (int c = 0; c < 40; ++c) {
                const float* Wc = Wp + c * 512;   // wave-uniform -> scalar path
                float a = acc[c];
#pragma unroll
                for (int k = 0; k < 32; ++k) a = fmaf(xv[k], Wc[k], a);
                acc[c] = a;
            }
        }
    }
    if (row < N) {
        float di = dinv[row];
        float4* zo = reinterpret_cast<float4*>(z + (size_t)row * 40);
#pragma unroll
        for (int c4 = 0; c4 < 10; ++c4)
            zo[c4] = make_float4(di * acc[c4*4], di * acc[c4*4+1],
                                 di * acc[c4*4+2], di * acc[c4*4+3]);
    }
}

// ---- gather hop: out[d] = dinv[d]^P * (z[d] + sum_{s in N(d)} z[s]) ----
// 10 threads per node, one float4 chunk each; register accumulation.
template <int P>
__global__ __launch_bounds__(TPB) void k_hop_csr(
    const int* __restrict__ csr, const int* __restrict__ row_ptr,
    const float* __restrict__ dinv, const float* __restrict__ zin,
    float* __restrict__ out, int N) {
    int t = blockIdx.x * TPB + threadIdx.x;
    int node = t / 10;
    int c4 = t - node * 10;
    if (node >= N) return;
    const float4* Z = reinterpret_cast<const float4*>(zin);
    float4 acc = Z[node * 10 + c4];            // self-loop term (z includes dinv)
    int beg = row_ptr[node];
    int end = row_ptr[node + 1];
    for (int j = beg; j < end; ++j) {
        int s = csr[j];                        // broadcast across the 10 lanes
        float4 v = Z[s * 10 + c4];
        acc.x += v.x; acc.y += v.y; acc.z += v.z; acc.w += v.w;
    }
    float dd = dinv[node];
    float sc = (P == 2) ? dd * dd : dd;
    float4 o = make_float4(sc*acc.x, sc*acc.y, sc*acc.z, sc*acc.w);
    reinterpret_cast<float4*>(out)[node * 10 + c4] = o;
}

// ---- log_softmax rows, in place on d_out, + bias -----------------------
__global__ __launch_bounds__(TPB) void k_logsoftmax(
    float* __restrict__ out, const float* __restrict__ b, int N) {
    int r = blockIdx.x * TPB + threadIdx.x;
    if (r >= N) return;
    float4* rowp = reinterpret_cast<float4*>(out + (size_t)r * 40);
    float v[40];
    float m = -1e30f;
#pragma unroll
    for (int c4 = 0; c4 < 10; ++c4) {
        float4 t = rowp[c4];
        v[c4*4+0] = t.x + b[c4*4+0];
        v[c4*4+1] = t.y + b[c4*4+1];
        v[c4*4+2] = t.z + b[c4*4+2];
        v[c4*4+3] = t.w + b[c4*4+3];
    }
#pragma unroll
    for (int c = 0; c < 40; ++c) m = fmaxf(m, v[c]);
    float sum = 0.f;
#pragma unroll
    for (int c = 0; c < 40; ++c) sum += __expf(v[c] - m);
    float lse = m + __logf(sum);
#pragma unroll
    for (int c4 = 0; c4 < 10; ++c4)
        rowp[c4] = make_float4(v[c4*4+0]-lse, v[c4*4+1]-lse, v[c4*4+2]-lse, v[c4*4+3]-lse);
}

extern "C" void kernel_launch(void* const* d_in, const int* in_sizes, int n_in,
                              void* d_out, int out_size, void* d_ws, size_t ws_size,
                              hipStream_t stream) {
    const float* x  = (const float*)d_in[0];
    const int*   ei = (const int*)d_in[1];
    const float* W  = (const float*)d_in[2];
    const float* b  = (const float*)d_in[3];
    float* out = (float*)d_out;

    const int N = in_sizes[0] / 512;     // 100000
    const int E = in_sizes[1] / 2;       // 3200000
    const int* src = ei;                 // edge_index[0]
    const int* dst = ei + E;             // edge_index[1]

    // workspace: z1 [N*40 f32] | csr [E i32] | counts [N] | row_ptr [N+1] | cursor [N] | dinv [N f32]
    float* z1      = (float*)d_ws;
    int*   csr     = (int*)(z1 + (size_t)N * 40);
    int*   counts  = csr + E;
    int*   row_ptr = counts + N;
    int*   cursor  = row_ptr + N + 1;
    float* dinv    = (float*)(cursor + N);
    float* z0      = out;                // stage z0 in d_out, overwritten by hop2

    hipMemsetAsync(counts, 0, (size_t)N * sizeof(int), stream);

    int gN = (N + TPB - 1) / TPB;
    int gE = (E + TPB - 1) / TPB;
    int gM = (N + MM_T - 1) / MM_T;
    int gH = (N * 10 + TPB - 1) / TPB;

    k_hist<<<gE, TPB, 0, stream>>>(dst, counts, E);
    k_scan<<<1, SCAN_T, 0, stream>>>(counts, row_ptr, cursor, dinv, N);
    k_scatter<<<gE, TPB, 0, stream>>>(src, dst, cursor, csr, E);

    k_matmul_xwt<<<gM, MM_T, 0, stream>>>(x, W, dinv, z0, N);

    k_hop_csr<2><<<gH, TPB, 0, stream>>>(csr, row_ptr, dinv, z0, z1, N);   // hop 1
    k_hop_csr<1><<<gH, TPB, 0, stream>>>(csr, row_ptr, dinv, z1, out, N);  // hop 2

    k_logsoftmax<<<gN, TPB, 0, stream>>>(out, b, N);
}